// Round 2
// baseline (29109.329 us; speedup 1.0000x reference)
//
#include <hip/hip_runtime.h>

typedef short v8s __attribute__((ext_vector_type(8)));
typedef float v4f __attribute__((ext_vector_type(4)));

#define LDT 40  // gemm LDS row stride (32+8) bf16 elems -> 80B: 2-way bank alias (free, m136)

__device__ __forceinline__ ushort f2b(float f) {
  union { float f; unsigned u; } v; v.f = f;
  unsigned r = (v.u + 0x7fffu + ((v.u >> 16) & 1u)) >> 16;
  return (ushort)r;
}

__device__ __forceinline__ void atomicMaxFloat(float* a, float v) {
  if (v >= 0.f) atomicMax((int*)a, __float_as_int(v));
  else          atomicMin((unsigned*)a, __float_as_uint(v));
}

// ---------------- transpose + f32->bf16: in [K,N] f32 -> out [N,K] bf16 ----------------
__global__ void transpose_to_bf16(const float* __restrict__ in, ushort* __restrict__ out,
                                  int K, int N) {
  __shared__ float t[32][33];
  int k0 = blockIdx.x * 32, n0 = blockIdx.y * 32;
  int tx = threadIdx.x, ty = threadIdx.y;  // 32 x 8
  #pragma unroll
  for (int j = 0; j < 4; j++)
    t[ty + 8 * j][tx] = in[(size_t)(k0 + ty + 8 * j) * N + n0 + tx];
  __syncthreads();
  #pragma unroll
  for (int j = 0; j < 4; j++)
    out[(size_t)(n0 + ty + 8 * j) * K + k0 + tx] = f2b(t[tx][ty + 8 * j]);
}

// ---------------- generic MFMA GEMM: C = act(A @ Bt^T + bias) [+ residual] ----------------
// A [M,K] bf16 (row stride lda), Bt [N,K] bf16 (row stride ldb).
// act: 0 none, 1 gelu(erf), 2 tanh, 3 relu. resid: outF[off] += result (f32 RMW).
__global__ __launch_bounds__(256) void gemm_bt(
    const ushort* __restrict__ A, const ushort* __restrict__ Bt,
    const float* __restrict__ bias, float* outF, ushort* outB,
    int M, int N, int K, int lda, int ldb, int act, int resid) {
  int m0 = blockIdx.x * 128, n0 = blockIdx.y * 128;
  __shared__ alignas(16) ushort As[128 * LDT];
  __shared__ alignas(16) ushort Bs[128 * LDT];
  int tid = threadIdx.x;
  int wave = tid >> 6, lane = tid & 63, lrow = lane & 15, quad = lane >> 4;
  int wm = (wave >> 1) * 64, wn = (wave & 1) * 64;
  v4f acc[4][4];
  #pragma unroll
  for (int i = 0; i < 4; i++)
    #pragma unroll
    for (int j = 0; j < 4; j++) acc[i][j] = (v4f){0.f, 0.f, 0.f, 0.f};

  for (int k0 = 0; k0 < K; k0 += 32) {
    __syncthreads();
    #pragma unroll
    for (int q = tid; q < 512; q += 256) {
      int row = q >> 2, c8 = (q & 3) * 8;
      *(uint4*)&As[row * LDT + c8] = *(const uint4*)&A[(size_t)(m0 + row) * lda + k0 + c8];
      *(uint4*)&Bs[row * LDT + c8] = *(const uint4*)&Bt[(size_t)(n0 + row) * ldb + k0 + c8];
    }
    __syncthreads();
    v8s af[4], bf[4];
    #pragma unroll
    for (int i = 0; i < 4; i++) af[i] = *(v8s*)&As[(wm + i * 16 + lrow) * LDT + quad * 8];
    #pragma unroll
    for (int j = 0; j < 4; j++) bf[j] = *(v8s*)&Bs[(wn + j * 16 + lrow) * LDT + quad * 8];
    #pragma unroll
    for (int i = 0; i < 4; i++)
      #pragma unroll
      for (int j = 0; j < 4; j++)
        acc[i][j] = __builtin_amdgcn_mfma_f32_16x16x32_bf16(af[i], bf[j], acc[i][j], 0, 0, 0);
  }

  #pragma unroll
  for (int i = 0; i < 4; i++) {
    #pragma unroll
    for (int j = 0; j < 4; j++) {
      int row = m0 + wm + i * 16 + quad * 4;
      int col = n0 + wn + j * 16 + lrow;
      float bv = bias ? bias[col] : 0.f;
      #pragma unroll
      for (int r = 0; r < 4; r++) {
        float v = acc[i][j][r] + bv;
        if (act == 1)      v = 0.5f * v * (1.f + erff(v * 0.70710678118f));
        else if (act == 2) v = tanhf(v);
        else if (act == 3) v = fmaxf(v, 0.f);
        size_t off = (size_t)(row + r) * N + col;
        if (outF) { if (resid) v += outF[off]; outF[off] = v; }
        if (outB) outB[off] = f2b(v);
      }
    }
  }
}

// ---------------- fused attention: one block per (seq, head) within a chunk ----------------
// qkvc: [chunkTokens=16384, 2304] bf16 (Q|K|V interleaved per 12 heads x 64)
// ctxc: [16384, 768] bf16 output
__global__ __launch_bounds__(256) void fused_attn(
    const ushort* __restrict__ qkvc, const int* __restrict__ mask,
    ushort* __restrict__ ctxc, int seqBase) {
  int b = blockIdx.x;            // 0..1535
  int nl = b / 12, h = b % 12;
  const ushort* Q = qkvc + (size_t)nl * 128 * 2304 + h * 64;
  const ushort* K = Q + 768;
  const ushort* V = Q + 1536;
  __shared__ alignas(16) char sm[56832];
  ushort* QL = (ushort*)sm;             // 128 x 72  (18432 B)
  ushort* KL = (ushort*)(sm + 18432);   // 128 x 72  (18432 B)
  ushort* PL = (ushort*)sm;             // 128 x 136 (34816 B) -- aliases QL+KL after S phase
  ushort* VT = (ushort*)(sm + 36864);   // 64 x 136  (17408 B)
  float*  mh = (float*)(sm + 54272);    // 2 x 128
  float*  sh = (float*)(sm + 55296);    // 2 x 128
  float*  mkL = (float*)(sm + 56320);   // 128

  int tid = threadIdx.x;
  int wave = tid >> 6, lane = tid & 63, lrow = lane & 15, quad = lane >> 4;

  for (int q = tid; q < 1024; q += 256) {
    int row = q >> 3, c8 = (q & 7) * 8;
    *(uint4*)&QL[row * 72 + c8] = *(const uint4*)&Q[(size_t)row * 2304 + c8];
    *(uint4*)&KL[row * 72 + c8] = *(const uint4*)&K[(size_t)row * 2304 + c8];
  }
  for (int q = tid; q < 1024; q += 256) {
    int t = q >> 3, d8 = (q & 7) * 8;
    union { uint4 u; ushort s[8]; } cv;
    cv.u = *(const uint4*)&V[(size_t)t * 2304 + d8];
    #pragma unroll
    for (int j = 0; j < 8; j++) VT[(d8 + j) * 136 + t] = cv.s[j];
  }
  if (tid < 128) mkL[tid] = mask[(seqBase + nl) * 128 + tid] ? 0.f : -1e9f;
  __syncthreads();

  // ---- S = Q K^T (each wave: 64x64 tile) ----
  int wm = (wave >> 1) * 64, wn = (wave & 1) * 64;
  v4f s[4][4];
  #pragma unroll
  for (int i = 0; i < 4; i++)
    #pragma unroll
    for (int j = 0; j < 4; j++) s[i][j] = (v4f){0.f, 0.f, 0.f, 0.f};
  #pragma unroll
  for (int k0 = 0; k0 < 64; k0 += 32) {
    v8s aq[4], bk[4];
    #pragma unroll
    for (int i = 0; i < 4; i++) aq[i] = *(v8s*)&QL[(wm + i * 16 + lrow) * 72 + k0 + quad * 8];
    #pragma unroll
    for (int j = 0; j < 4; j++) bk[j] = *(v8s*)&KL[(wn + j * 16 + lrow) * 72 + k0 + quad * 8];
    #pragma unroll
    for (int i = 0; i < 4; i++)
      #pragma unroll
      for (int j = 0; j < 4; j++)
        s[i][j] = __builtin_amdgcn_mfma_f32_16x16x32_bf16(aq[i], bk[j], s[i][j], 0, 0, 0);
  }

  // ---- scale + mask, per-row max (half = col half this wave owns) ----
  #pragma unroll
  for (int i = 0; i < 4; i++) {
    #pragma unroll
    for (int r = 0; r < 4; r++) {
      float mx = -3e38f;
      #pragma unroll
      for (int j = 0; j < 4; j++) {
        float v = s[i][j][r] * 0.125f + mkL[wn + j * 16 + lrow];
        s[i][j][r] = v;
        mx = fmaxf(mx, v);
      }
      #pragma unroll
      for (int o = 1; o < 16; o <<= 1) mx = fmaxf(mx, __shfl_xor(mx, o, 64));
      if (lrow == 0) mh[(wave & 1) * 128 + wm + i * 16 + quad * 4 + r] = mx;
    }
  }
  __syncthreads();

  // ---- exp + per-row sum ----
  #pragma unroll
  for (int i = 0; i < 4; i++) {
    #pragma unroll
    for (int r = 0; r < 4; r++) {
      int row = wm + i * 16 + quad * 4 + r;
      float m = fmaxf(mh[row], mh[128 + row]);
      float sum = 0.f;
      #pragma unroll
      for (int j = 0; j < 4; j++) {
        float p = __expf(s[i][j][r] - m);
        s[i][j][r] = p;
        sum += p;
      }
      #pragma unroll
      for (int o = 1; o < 16; o <<= 1) sum += __shfl_xor(sum, o, 64);
      if (lrow == 0) sh[(wave & 1) * 128 + row] = sum;
    }
  }
  __syncthreads();

  // ---- alpha -> P in LDS (row-major, A-fragment-ready); PL aliases QL/KL ----
  #pragma unroll
  for (int i = 0; i < 4; i++) {
    #pragma unroll
    for (int r = 0; r < 4; r++) {
      int row = wm + i * 16 + quad * 4 + r;
      float inv = 1.f / (sh[row] + sh[128 + row]);
      #pragma unroll
      for (int j = 0; j < 4; j++)
        PL[row * 136 + wn + j * 16 + lrow] = f2b(s[i][j][r] * inv);
    }
  }
  __syncthreads();

  // ---- O = P V  (each wave: 32 rows x 64 cols) ----
  int wm2 = wave * 32;
  v4f o[2][4];
  #pragma unroll
  for (int i = 0; i < 2; i++)
    #pragma unroll
    for (int j = 0; j < 4; j++) o[i][j] = (v4f){0.f, 0.f, 0.f, 0.f};
  #pragma unroll
  for (int kk = 0; kk < 4; kk++) {
    v8s ap[2], bv[4];
    #pragma unroll
    for (int i = 0; i < 2; i++)
      ap[i] = *(v8s*)&PL[(wm2 + i * 16 + lrow) * 136 + kk * 32 + quad * 8];
    #pragma unroll
    for (int j = 0; j < 4; j++)
      bv[j] = *(v8s*)&VT[(j * 16 + lrow) * 136 + kk * 32 + quad * 8];
    #pragma unroll
    for (int i = 0; i < 2; i++)
      #pragma unroll
      for (int j = 0; j < 4; j++)
        o[i][j] = __builtin_amdgcn_mfma_f32_16x16x32_bf16(ap[i], bv[j], o[i][j], 0, 0, 0);
  }
  #pragma unroll
  for (int i = 0; i < 2; i++)
    #pragma unroll
    for (int j = 0; j < 4; j++)
      #pragma unroll
      for (int r = 0; r < 4; r++) {
        int row = wm2 + i * 16 + quad * 4 + r;
        int col = j * 16 + lrow;
        ctxc[(size_t)(nl * 128 + row) * 768 + h * 64 + col] = f2b(o[i][j][r]);
      }
}

// ---------------- embedding + LN (wave per token) ----------------
__global__ __launch_bounds__(256) void embed_ln(
    const int* __restrict__ ids, const float* __restrict__ wemb,
    const float* __restrict__ pemb, const float* __restrict__ temb,
    const float* __restrict__ g, const float* __restrict__ b,
    float* __restrict__ xf, ushort* __restrict__ xb) {
  int tok = blockIdx.x * 4 + (threadIdx.x >> 6);
  int lane = threadIdx.x & 63;
  int t = tok & 127;
  int id = ids[tok];
  float v[12];
  float s = 0.f;
  #pragma unroll
  for (int k = 0; k < 12; k++) {
    int d = k * 64 + lane;
    v[k] = wemb[(size_t)id * 768 + d] + pemb[(size_t)(t + 2) * 768 + d] + temb[d];
    s += v[k];
  }
  #pragma unroll
  for (int o = 32; o; o >>= 1) s += __shfl_xor(s, o, 64);
  float mean = s * (1.f / 768.f);
  float vs = 0.f;
  #pragma unroll
  for (int k = 0; k < 12; k++) { float d = v[k] - mean; vs += d * d; }
  #pragma unroll
  for (int o = 32; o; o >>= 1) vs += __shfl_xor(vs, o, 64);
  float rstd = rsqrtf(vs * (1.f / 768.f) + 1e-5f);
  #pragma unroll
  for (int k = 0; k < 12; k++) {
    int d = k * 64 + lane;
    float ov = (v[k] - mean) * rstd * g[d] + b[d];
    xf[(size_t)tok * 768 + d] = ov;
    xb[(size_t)tok * 768 + d] = f2b(ov);
  }
}

// ---------------- in-place LN: x = LN(x) (wave per token) ----------------
__global__ __launch_bounds__(256) void ln_inplace(
    float* __restrict__ xf, const float* __restrict__ g, const float* __restrict__ b,
    ushort* __restrict__ xb) {
  int tok = blockIdx.x * 4 + (threadIdx.x >> 6);
  int lane = threadIdx.x & 63;
  float v[12];
  float s = 0.f;
  #pragma unroll
  for (int k = 0; k < 12; k++) { v[k] = xf[(size_t)tok * 768 + k * 64 + lane]; s += v[k]; }
  #pragma unroll
  for (int o = 32; o; o >>= 1) s += __shfl_xor(s, o, 64);
  float mean = s * (1.f / 768.f);
  float vs = 0.f;
  #pragma unroll
  for (int k = 0; k < 12; k++) { float d = v[k] - mean; vs += d * d; }
  #pragma unroll
  for (int o = 32; o; o >>= 1) vs += __shfl_xor(vs, o, 64);
  float rstd = rsqrtf(vs * (1.f / 768.f) + 1e-5f);
  #pragma unroll
  for (int k = 0; k < 12; k++) {
    int d = k * 64 + lane;
    float ov = (v[k] - mean) * rstd * g[d] + b[d];
    xf[(size_t)tok * 768 + d] = ov;
    xb[(size_t)tok * 768 + d] = f2b(ov);
  }
}

// ---------------- pooler gather ----------------
__global__ void gather_cls(const float* __restrict__ xf, ushort* __restrict__ out) {
  int n = blockIdx.x;
  for (int d = threadIdx.x; d < 768; d += 256)
    out[(size_t)n * 768 + d] = f2b(xf[(size_t)n * 128 * 768 + d]);
}

// ---------------- GAT pieces ----------------
__device__ __forceinline__ float blockSum256(float v) {
  __shared__ float sb[4];
  #pragma unroll
  for (int o = 32; o; o >>= 1) v += __shfl_xor(v, o, 64);
  int w = threadIdx.x >> 6;
  __syncthreads();
  if ((threadIdx.x & 63) == 0) sb[w] = v;
  __syncthreads();
  return sb[0] + sb[1] + sb[2] + sb[3];
}

__global__ __launch_bounds__(256) void gat_coeff(
    const float* __restrict__ h, const float* __restrict__ asrc,
    const float* __restrict__ adst, float* __restrict__ asr, float* __restrict__ ads,
    int ncols, int heads) {
  int n = blockIdx.x;
  int cc = ncols / heads;
  for (int hh = 0; hh < heads; hh++) {
    float vs = 0.f, vd = 0.f;
    if ((int)threadIdx.x < cc) {
      float hv = h[(size_t)n * ncols + hh * cc + threadIdx.x];
      vs = hv * asrc[hh * cc + threadIdx.x];
      vd = hv * adst[hh * cc + threadIdx.x];
    }
    float ss = blockSum256(vs);
    float sd = blockSum256(vd);
    if (threadIdx.x == 0) { asr[n * heads + hh] = ss; ads[n * heads + hh] = sd; }
  }
}

__global__ void gat_init(float* m, float* s, float* agg, int heads, int aggCols) {
  int n = blockIdx.x;
  if ((int)threadIdx.x < heads) {
    m[n * heads + threadIdx.x] = -1e30f;
    s[n * heads + threadIdx.x] = 0.f;
  }
  for (int c = threadIdx.x; c < aggCols; c += 256) agg[(size_t)n * aggCols + c] = 0.f;
}

__global__ void gat_edge_max(const int* __restrict__ ei, const float* __restrict__ asr,
                             const float* __restrict__ ads, float* __restrict__ m,
                             int heads, int E) {
  int e = blockIdx.x * 256 + threadIdx.x;
  if (e >= E + 512) return;
  int s, d;
  if (e < E) { s = ei[e]; d = ei[E + e]; } else { s = d = e - E; }
  for (int hh = 0; hh < heads; hh++) {
    float v = asr[s * heads + hh] + ads[d * heads + hh];
    v = v > 0.f ? v : 0.2f * v;
    atomicMaxFloat(&m[d * heads + hh], v);
  }
}

__global__ void gat_edge_agg(const int* __restrict__ ei, const float* __restrict__ asr,
                             const float* __restrict__ ads, const float* __restrict__ m,
                             const float* __restrict__ hfeat, float* __restrict__ sden,
                             float* __restrict__ agg, int heads, int cc, int E) {
  int e = blockIdx.x;
  int s, d;
  if (e < E) { s = ei[e]; d = ei[E + e]; } else { s = d = e - E; }
  int ncols = heads * cc;
  for (int hh = 0; hh < heads; hh++) {
    float v = asr[s * heads + hh] + ads[d * heads + hh];
    v = v > 0.f ? v : 0.2f * v;
    float p = expf(v - m[d * heads + hh]);
    if (threadIdx.x == 0) atomicAdd(&sden[d * heads + hh], p);
    int c = hh * cc + threadIdx.x;
    atomicAdd(&agg[(size_t)d * ncols + c], p * hfeat[(size_t)s * ncols + c]);
  }
}

__global__ void gat_finalize(const float* __restrict__ agg, const float* __restrict__ sden,
                             const float* __restrict__ bias, float* outF, ushort* outB,
                             float* outExtra, int heads, int cc, int doElu) {
  int n = blockIdx.x;
  int ncols = heads * cc;
  for (int c = threadIdx.x; c < ncols; c += blockDim.x) {
    int hh = c / cc;
    float v = agg[(size_t)n * ncols + c] / (sden[n * heads + hh] + 1e-16f) + bias[c];
    if (doElu) v = v > 0.f ? v : expm1f(v);
    if (outF) outF[(size_t)n * ncols + c] = v;
    outB[(size_t)n * ncols + c] = f2b(v);
    if (outExtra) outExtra[(size_t)n * ncols + c] = v;
  }
}

// ---------------- heads ----------------
__global__ __launch_bounds__(256) void feat_norm(const float* __restrict__ f,
                                                 float* __restrict__ out) {
  int n = blockIdx.x * 2 + (threadIdx.x >> 7);
  int lane = threadIdx.x & 127;
  int l64 = lane & 63;
  float x = f[n * 128 + lane];
  float v = x * x;
  // reduce across the two waves covering this n? lanes 0..127 span 2 waves.
  // simpler: each 128-lane group is 2 waves; do per-wave then LDS combine.
  __shared__ float sb[4];
  #pragma unroll
  for (int o = 32; o; o >>= 1) v += __shfl_xor(v, o, 64);
  int w = threadIdx.x >> 6;
  __syncthreads();
  if (l64 == 0) sb[w] = v;
  __syncthreads();
  float ss = sb[(threadIdx.x >> 7) * 2] + sb[(threadIdx.x >> 7) * 2 + 1];
  float sc = 1.f / fmaxf(sqrtf(ss), 1e-12f);
  out[n * 128 + lane] = x * sc;
}

__global__ void cls_head(const float* __restrict__ h2, const float* __restrict__ w,
                         const float* __restrict__ b, float* __restrict__ out) {
  int idx = blockIdx.x * 256 + threadIdx.x;
  if (idx >= 1024) return;
  int n = idx >> 1, c = idx & 1;
  float acc = b[c];
  for (int k = 0; k < 128; k++) acc += h2[n * 128 + k] * w[k * 2 + c];
  out[idx] = acc;
}

// ==================================================================================
extern "C" void kernel_launch(void* const* d_in, const int* in_sizes, int n_in,
                              void* d_out, int out_size, void* d_ws, size_t ws_size,
                              hipStream_t stream) {
  const int*   input_ids = (const int*)d_in[0];
  const int*   attn_mask = (const int*)d_in[1];
  const int*   edge_idx  = (const int*)d_in[2];
  const float* word_emb  = (const float*)d_in[3];
  const float* pos_emb   = (const float*)d_in[4];
  const float* type_emb  = (const float*)d_in[5];
  const float* ln_emb_s  = (const float*)d_in[6];
  const float* ln_emb_b  = (const float*)d_in[7];
  const float* Wqkv      = (const float*)d_in[8];
  const float* bqkv      = (const float*)d_in[9];
  const float* Wo        = (const float*)d_in[10];
  const float* bo        = (const float*)d_in[11];
  const float* ln1_s     = (const float*)d_in[12];
  const float* ln1_b     = (const float*)d_in[13];
  const float* Wff1      = (const float*)d_in[14];
  const float* bff1      = (const float*)d_in[15];
  const float* Wff2      = (const float*)d_in[16];
  const float* bff2      = (const float*)d_in[17];
  const float* ln2_s     = (const float*)d_in[18];
  const float* ln2_b     = (const float*)d_in[19];
  const float* pool_w    = (const float*)d_in[20];
  const float* pool_b    = (const float*)d_in[21];
  const float* gat1_w    = (const float*)d_in[22];
  const float* gat1_asrc = (const float*)d_in[23];
  const float* gat1_adst = (const float*)d_in[24];
  const float* gat1_b    = (const float*)d_in[25];
  const float* gat2_w    = (const float*)d_in[26];
  const float* gat2_asrc = (const float*)d_in[27];
  const float* gat2_adst = (const float*)d_in[28];
  const float* gat2_b    = (const float*)d_in[29];
  const float* proj_w1   = (const float*)d_in[30];
  const float* proj_b1   = (const float*)d_in[31];
  const float* proj_w2   = (const float*)d_in[32];
  const float* proj_b2   = (const float*)d_in[33];
  const float* cls_w     = (const float*)d_in[34];
  const float* cls_b     = (const float*)d_in[35];
  float* out = (float*)d_out;

  const int E = in_sizes[2] / 2;   // 32768
  const int ET = E + 512;
  const int M = 512 * 128;         // 65536 tokens
  const int CH = 16384;            // tokens per chunk (128 seqs)

  char* cur = (char*)d_ws;
  auto alloc = [&](size_t bytes) -> void* {
    void* p = (void*)cur;
    cur += (bytes + 255) & ~(size_t)255;
    return p;
  };

  // per-layer weight staging (reused each layer)
  ushort* WqkvT = (ushort*)alloc((size_t)2304 * 768 * 2);
  ushort* WoT   = (ushort*)alloc((size_t)768 * 768 * 2);
  ushort* Wff1T = (ushort*)alloc((size_t)3072 * 768 * 2);
  ushort* Wff2T = (ushort*)alloc((size_t)768 * 3072 * 2);
  // head weights
  ushort* PoolT = (ushort*)alloc((size_t)768 * 768 * 2);
  ushort* G1T   = (ushort*)alloc((size_t)1024 * 768 * 2);
  ushort* G2T   = (ushort*)alloc((size_t)128 * 1024 * 2);
  ushort* P1T   = (ushort*)alloc((size_t)128 * 128 * 2);
  ushort* P2T   = (ushort*)alloc((size_t)128 * 128 * 2);
  // activations
  float*  x_f32 = (float*)alloc((size_t)M * 768 * 4);    // 201.3 MB residual stream
  ushort* x_bf  = (ushort*)alloc((size_t)M * 768 * 2);   // 100.7 MB
  char*   arena = (char*)alloc((size_t)CH * 3072 * 2);   // 100.7 MB: qkvc+ctxc | ffc
  ushort* qkvc  = (ushort*)arena;                        // [CH,2304] = 75.5 MB
  ushort* ctxc  = (ushort*)(arena + (size_t)CH * 2304 * 2);  // [CH,768] = 25.2 MB
  ushort* ffc   = (ushort*)arena;                        // [CH,3072] = 100.7 MB
  // heads / GAT
  ushort* cls_bf   = (ushort*)alloc((size_t)512 * 768 * 2);
  ushort* htext_bf = (ushort*)alloc((size_t)512 * 768 * 2);
  float*  h1g      = (float*)alloc((size_t)512 * 1024 * 4);
  float*  asr1     = (float*)alloc(512 * 4 * 4);
  float*  ads1     = (float*)alloc(512 * 4 * 4);
  float*  m1       = (float*)alloc(512 * 4 * 4);
  float*  s1       = (float*)alloc(512 * 4 * 4);
  float*  agg1     = (float*)alloc((size_t)512 * 1024 * 4);
  ushort* h1_bf    = (ushort*)alloc((size_t)512 * 1024 * 2);
  float*  h2g      = (float*)alloc((size_t)512 * 128 * 4);
  float*  asr2     = (float*)alloc(512 * 4);
  float*  ads2     = (float*)alloc(512 * 4);
  float*  m2       = (float*)alloc(512 * 4);
  float*  s2       = (float*)alloc(512 * 4);
  float*  agg2     = (float*)alloc((size_t)512 * 128 * 4);
  float*  h2f      = (float*)alloc((size_t)512 * 128 * 4);
  ushort* h2_bf    = (ushort*)alloc((size_t)512 * 128 * 2);
  ushort* p1_bf    = (ushort*)alloc((size_t)512 * 128 * 2);
  float*  featpre  = (float*)alloc((size_t)512 * 128 * 4);

  auto T = [&](const float* in, ushort* o, int K, int N) {
    transpose_to_bf16<<<dim3(K / 32, N / 32), dim3(32, 8), 0, stream>>>(in, o, K, N);
  };

  // head weights once
  T(pool_w, PoolT, 768, 768);
  T(gat1_w, G1T, 768, 1024);
  T(gat2_w, G2T, 1024, 128);
  T(proj_w1, P1T, 128, 128);
  T(proj_w2, P2T, 128, 128);

  embed_ln<<<M / 4, 256, 0, stream>>>(input_ids, word_emb, pos_emb, type_emb,
                                      ln_emb_s, ln_emb_b, x_f32, x_bf);

  for (int i = 0; i < 12; i++) {
    T(Wqkv + (size_t)i * 768 * 2304, WqkvT, 768, 2304);
    T(Wo   + (size_t)i * 768 * 768,  WoT,   768, 768);
    T(Wff1 + (size_t)i * 768 * 3072, Wff1T, 768, 3072);
    T(Wff2 + (size_t)i * 3072 * 768, Wff2T, 3072, 768);

    // attention (chunked over 4 groups of 128 sequences)
    for (int c = 0; c < 4; c++) {
      size_t off = (size_t)c * CH;
      gemm_bt<<<dim3(CH / 128, 18), 256, 0, stream>>>(
          x_bf + off * 768, WqkvT, bqkv + (size_t)i * 2304,
          nullptr, qkvc, CH, 2304, 768, 768, 768, 0, 0);
      fused_attn<<<1536, 256, 0, stream>>>(qkvc, attn_mask, ctxc, c * 128);
      gemm_bt<<<dim3(CH / 128, 6), 256, 0, stream>>>(
          ctxc, WoT, bo + (size_t)i * 768,
          x_f32 + off * 768, nullptr, CH, 768, 768, 768, 768, 0, 1);
    }
    ln_inplace<<<M / 4, 256, 0, stream>>>(x_f32, ln1_s + (size_t)i * 768,
                                          ln1_b + (size_t)i * 768, x_bf);
    // FFN (chunked)
    for (int c = 0; c < 4; c++) {
      size_t off = (size_t)c * CH;
      gemm_bt<<<dim3(CH / 128, 24), 256, 0, stream>>>(
          x_bf + off * 768, Wff1T, bff1 + (size_t)i * 3072,
          nullptr, ffc, CH, 3072, 768, 768, 768, 1, 0);
      gemm_bt<<<dim3(CH / 128, 6), 256, 0, stream>>>(
          ffc, Wff2T, bff2 + (size_t)i * 768,
          x_f32 + off * 768, nullptr, CH, 768, 3072, 3072, 3072, 0, 1);
    }
    ln_inplace<<<M / 4, 256, 0, stream>>>(x_f32, ln2_s + (size_t)i * 768,
                                          ln2_b + (size_t)i * 768, x_bf);
  }

  gather_cls<<<512, 256, 0, stream>>>(x_f32, cls_bf);
  gemm_bt<<<dim3(4, 6), 256, 0, stream>>>(cls_bf, PoolT, pool_b, nullptr, htext_bf,
                                          512, 768, 768, 768, 768, 2, 0);
  gemm_bt<<<dim3(4, 8), 256, 0, stream>>>(htext_bf, G1T, nullptr, h1g, nullptr,
                                          512, 1024, 768, 768, 768, 0, 0);
  gat_coeff<<<512, 256, 0, stream>>>(h1g, gat1_asrc, gat1_adst, asr1, ads1, 1024, 4);
  gat_init<<<512, 256, 0, stream>>>(m1, s1, agg1, 4, 1024);
  gat_edge_max<<<(ET + 255) / 256, 256, 0, stream>>>(edge_idx, asr1, ads1, m1, 4, E);
  gat_edge_agg<<<ET, 256, 0, stream>>>(edge_idx, asr1, ads1, m1, h1g, s1, agg1, 4, 256, E);
  gat_finalize<<<512, 256, 0, stream>>>(agg1, s1, gat1_b, nullptr, h1_bf, nullptr, 4, 256, 1);

  gemm_bt<<<dim3(4, 1), 256, 0, stream>>>(h1_bf, G2T, nullptr, h2g, nullptr,
                                          512, 128, 1024, 1024, 1024, 0, 0);
  gat_coeff<<<512, 256, 0, stream>>>(h2g, gat2_asrc, gat2_adst, asr2, ads2, 128, 1);
  gat_init<<<512, 256, 0, stream>>>(m2, s2, agg2, 1, 128);
  gat_edge_max<<<(ET + 255) / 256, 256, 0, stream>>>(edge_idx, asr2, ads2, m2, 1, E);
  gat_edge_agg<<<ET, 128, 0, stream>>>(edge_idx, asr2, ads2, m2, h2g, s2, agg2, 1, 128, E);
  gat_finalize<<<512, 256, 0, stream>>>(agg2, s2, gat2_b, h2f, h2_bf, out + 66560, 1, 128, 0);

  gemm_bt<<<dim3(4, 1), 256, 0, stream>>>(h2_bf, P1T, proj_b1, nullptr, p1_bf,
                                          512, 128, 128, 128, 128, 3, 0);
  gemm_bt<<<dim3(4, 1), 256, 0, stream>>>(p1_bf, P2T, proj_b2, featpre, nullptr,
                                          512, 128, 128, 128, 128, 0, 0);
  feat_norm<<<256, 256, 0, stream>>>(featpre, out + 1024);
  cls_head<<<4, 256, 0, stream>>>(h2f, cls_w, cls_b, out);
}

// Round 3
// 27340.002 us; speedup vs baseline: 1.0647x; 1.0647x over previous
//
#include <hip/hip_runtime.h>

typedef short v8s __attribute__((ext_vector_type(8)));
typedef float v4f __attribute__((ext_vector_type(4)));

__device__ __forceinline__ ushort f2b(float f) {
  union { float f; unsigned u; } v; v.f = f;
  unsigned r = (v.u + 0x7fffu + ((v.u >> 16) & 1u)) >> 16;
  return (ushort)r;
}

__device__ __forceinline__ void atomicMaxFloat(float* a, float v) {
  if (v >= 0.f) atomicMax((int*)a, __float_as_int(v));
  else          atomicMin((unsigned*)a, __float_as_uint(v));
}

// async global->LDS, 16B per lane; LDS dest = wave-uniform base + lane*16B (m97/m104)
__device__ __forceinline__ void gl2lds16(const ushort* g, ushort* l) {
  __builtin_amdgcn_global_load_lds((const __attribute__((address_space(1))) void*)g,
                                   (__attribute__((address_space(3))) void*)l, 16, 0, 0);
}

// ---------------- transpose + f32->bf16: in [K,N] f32 -> out [N,K] bf16 ----------------
__global__ void transpose_to_bf16(const float* __restrict__ in, ushort* __restrict__ out,
                                  int K, int N) {
  __shared__ float t[32][33];
  int k0 = blockIdx.x * 32, n0 = blockIdx.y * 32;
  int tx = threadIdx.x, ty = threadIdx.y;  // 32 x 8
  #pragma unroll
  for (int j = 0; j < 4; j++)
    t[ty + 8 * j][tx] = in[(size_t)(k0 + ty + 8 * j) * N + n0 + tx];
  __syncthreads();
  #pragma unroll
  for (int j = 0; j < 4; j++)
    out[(size_t)(n0 + ty + 8 * j) * K + k0 + tx] = f2b(t[tx][ty + 8 * j]);
}

// ---------------- generic MFMA GEMM: C = act(A @ Bt^T + bias) [+ residual] ----------------
// A [M,K] bf16 (row stride lda), Bt [N,K] bf16 (row stride ldb). M,N mult of 128, K mult of 32.
// act: 0 none, 1 gelu(erf), 2 tanh, 3 relu. resid: outF[off] += result (f32 RMW).
// Staging via global_load_lds width=16 (m97): LDS tiles 128x32, NO padding (DMA layout).
__global__ __launch_bounds__(256) void gemm_bt(
    const ushort* __restrict__ A, const ushort* __restrict__ Bt,
    const float* __restrict__ bias, float* outF, ushort* outB,
    int M, int N, int K, int lda, int ldb, int act, int resid) {
  int m0 = blockIdx.x * 128, n0 = blockIdx.y * 128;
  __shared__ alignas(16) ushort As[128 * 32];
  __shared__ alignas(16) ushort Bs[128 * 32];
  int tid = threadIdx.x;
  int wave = tid >> 6, lane = tid & 63, lrow = lane & 15, quad = lane >> 4;
  int wm = (wave >> 1) * 64, wn = (wave & 1) * 64;

  // staging: wave w, issue i covers rows i*64 + w*16 .. +15; lane l -> row +(l>>2), col (l&3)*8
  int srow = wave * 16 + (lane >> 2);
  int scol = (lane & 3) * 8;
  const ushort* gA0 = A  + (size_t)(m0 + srow) * lda + scol;
  const ushort* gA1 = gA0 + (size_t)64 * lda;
  const ushort* gB0 = Bt + (size_t)(n0 + srow) * ldb + scol;
  const ushort* gB1 = gB0 + (size_t)64 * ldb;
  ushort* lA0 = As + wave * 16 * 32;
  ushort* lA1 = lA0 + 64 * 32;
  ushort* lB0 = Bs + wave * 16 * 32;
  ushort* lB1 = lB0 + 64 * 32;

  v4f acc[4][4];
  #pragma unroll
  for (int i = 0; i < 4; i++)
    #pragma unroll
    for (int j = 0; j < 4; j++) acc[i][j] = (v4f){0.f, 0.f, 0.f, 0.f};

  for (int k0 = 0; k0 < K; k0 += 32) {
    __syncthreads();
    gl2lds16(gA0 + k0, lA0);
    gl2lds16(gA1 + k0, lA1);
    gl2lds16(gB0 + k0, lB0);
    gl2lds16(gB1 + k0, lB1);
    __syncthreads();
    v8s af[4], bf[4];
    #pragma unroll
    for (int i = 0; i < 4; i++) af[i] = *(v8s*)&As[(wm + i * 16 + lrow) * 32 + quad * 8];
    #pragma unroll
    for (int j = 0; j < 4; j++) bf[j] = *(v8s*)&Bs[(wn + j * 16 + lrow) * 32 + quad * 8];
    #pragma unroll
    for (int i = 0; i < 4; i++)
      #pragma unroll
      for (int j = 0; j < 4; j++)
        acc[i][j] = __builtin_amdgcn_mfma_f32_16x16x32_bf16(af[i], bf[j], acc[i][j], 0, 0, 0);
  }

  #pragma unroll
  for (int i = 0; i < 4; i++) {
    #pragma unroll
    for (int j = 0; j < 4; j++) {
      int row = m0 + wm + i * 16 + quad * 4;
      int col = n0 + wn + j * 16 + lrow;
      float bv = bias ? bias[col] : 0.f;
      #pragma unroll
      for (int r = 0; r < 4; r++) {
        float v = acc[i][j][r] + bv;
        if (act == 1)      v = 0.5f * v * (1.f + erff(v * 0.70710678118f));
        else if (act == 2) v = tanhf(v);
        else if (act == 3) v = fmaxf(v, 0.f);
        size_t off = (size_t)(row + r) * N + col;
        if (outF) { if (resid) v += outF[off]; outF[off] = v; }
        if (outB) outB[off] = f2b(v);
      }
    }
  }
}

// ---------------- fused attention: one block per (seq, head) within a chunk ----------------
// qkvc: [chunkTokens=16384, 2304] bf16 (Q|K|V interleaved per 12 heads x 64)
// ctxc: [16384, 768] bf16 output
__global__ __launch_bounds__(256) void fused_attn(
    const ushort* __restrict__ qkvc, const int* __restrict__ mask,
    ushort* __restrict__ ctxc, int seqBase) {
  int b = blockIdx.x;            // 0..1535
  int nl = b / 12, h = b % 12;
  const ushort* Q = qkvc + (size_t)nl * 128 * 2304 + h * 64;
  const ushort* K = Q + 768;
  const ushort* V = Q + 1536;
  __shared__ alignas(16) char sm[56832];
  ushort* QL = (ushort*)sm;             // 128 x 72  (18432 B)
  ushort* KL = (ushort*)(sm + 18432);   // 128 x 72  (18432 B)
  ushort* PL = (ushort*)sm;             // 128 x 136 (34816 B) -- aliases QL+KL after S phase
  ushort* VT = (ushort*)(sm + 36864);   // 64 x 136  (17408 B)
  float*  mh = (float*)(sm + 54272);    // 2 x 128
  float*  sh = (float*)(sm + 55296);    // 2 x 128
  float*  mkL = (float*)(sm + 56320);   // 128

  int tid = threadIdx.x;
  int wave = tid >> 6, lane = tid & 63, lrow = lane & 15, quad = lane >> 4;

  for (int q = tid; q < 1024; q += 256) {
    int row = q >> 3, c8 = (q & 7) * 8;
    *(uint4*)&QL[row * 72 + c8] = *(const uint4*)&Q[(size_t)row * 2304 + c8];
    *(uint4*)&KL[row * 72 + c8] = *(const uint4*)&K[(size_t)row * 2304 + c8];
  }
  for (int q = tid; q < 1024; q += 256) {
    int t = q >> 3, d8 = (q & 7) * 8;
    union { uint4 u; ushort s[8]; } cv;
    cv.u = *(const uint4*)&V[(size_t)t * 2304 + d8];
    #pragma unroll
    for (int j = 0; j < 8; j++) VT[(d8 + j) * 136 + t] = cv.s[j];
  }
  if (tid < 128) mkL[tid] = mask[(seqBase + nl) * 128 + tid] ? 0.f : -1e9f;
  __syncthreads();

  // ---- S = Q K^T (each wave: 64x64 tile) ----
  int wm = (wave >> 1) * 64, wn = (wave & 1) * 64;
  v4f s[4][4];
  #pragma unroll
  for (int i = 0; i < 4; i++)
    #pragma unroll
    for (int j = 0; j < 4; j++) s[i][j] = (v4f){0.f, 0.f, 0.f, 0.f};
  #pragma unroll
  for (int k0 = 0; k0 < 64; k0 += 32) {
    v8s aq[4], bk[4];
    #pragma unroll
    for (int i = 0; i < 4; i++) aq[i] = *(v8s*)&QL[(wm + i * 16 + lrow) * 72 + k0 + quad * 8];
    #pragma unroll
    for (int j = 0; j < 4; j++) bk[j] = *(v8s*)&KL[(wn + j * 16 + lrow) * 72 + k0 + quad * 8];
    #pragma unroll
    for (int i = 0; i < 4; i++)
      #pragma unroll
      for (int j = 0; j < 4; j++)
        s[i][j] = __builtin_amdgcn_mfma_f32_16x16x32_bf16(aq[i], bk[j], s[i][j], 0, 0, 0);
  }

  // ---- scale + mask, per-row max (half = col half this wave owns) ----
  #pragma unroll
  for (int i = 0; i < 4; i++) {
    #pragma unroll
    for (int r = 0; r < 4; r++) {
      float mx = -3e38f;
      #pragma unroll
      for (int j = 0; j < 4; j++) {
        float v = s[i][j][r] * 0.125f + mkL[wn + j * 16 + lrow];
        s[i][j][r] = v;
        mx = fmaxf(mx, v);
      }
      #pragma unroll
      for (int o = 1; o < 16; o <<= 1) mx = fmaxf(mx, __shfl_xor(mx, o, 64));
      if (lrow == 0) mh[(wave & 1) * 128 + wm + i * 16 + quad * 4 + r] = mx;
    }
  }
  __syncthreads();

  // ---- exp + per-row sum ----
  #pragma unroll
  for (int i = 0; i < 4; i++) {
    #pragma unroll
    for (int r = 0; r < 4; r++) {
      int row = wm + i * 16 + quad * 4 + r;
      float m = fmaxf(mh[row], mh[128 + row]);
      float sum = 0.f;
      #pragma unroll
      for (int j = 0; j < 4; j++) {
        float p = __expf(s[i][j][r] - m);
        s[i][j][r] = p;
        sum += p;
      }
      #pragma unroll
      for (int o = 1; o < 16; o <<= 1) sum += __shfl_xor(sum, o, 64);
      if (lrow == 0) sh[(wave & 1) * 128 + row] = sum;
    }
  }
  __syncthreads();

  // ---- alpha -> P in LDS (row-major, A-fragment-ready); PL aliases QL/KL ----
  #pragma unroll
  for (int i = 0; i < 4; i++) {
    #pragma unroll
    for (int r = 0; r < 4; r++) {
      int row = wm + i * 16 + quad * 4 + r;
      float inv = 1.f / (sh[row] + sh[128 + row]);
      #pragma unroll
      for (int j = 0; j < 4; j++)
        PL[row * 136 + wn + j * 16 + lrow] = f2b(s[i][j][r] * inv);
    }
  }
  __syncthreads();

  // ---- O = P V  (each wave: 32 rows x 64 cols) ----
  int wm2 = wave * 32;
  v4f o[2][4];
  #pragma unroll
  for (int i = 0; i < 2; i++)
    #pragma unroll
    for (int j = 0; j < 4; j++) o[i][j] = (v4f){0.f, 0.f, 0.f, 0.f};
  #pragma unroll
  for (int kk = 0; kk < 4; kk++) {
    v8s ap[2], bv[4];
    #pragma unroll
    for (int i = 0; i < 2; i++)
      ap[i] = *(v8s*)&PL[(wm2 + i * 16 + lrow) * 136 + kk * 32 + quad * 8];
    #pragma unroll
    for (int j = 0; j < 4; j++)
      bv[j] = *(v8s*)&VT[(j * 16 + lrow) * 136 + kk * 32 + quad * 8];
    #pragma unroll
    for (int i = 0; i < 2; i++)
      #pragma unroll
      for (int j = 0; j < 4; j++)
        o[i][j] = __builtin_amdgcn_mfma_f32_16x16x32_bf16(ap[i], bv[j], o[i][j], 0, 0, 0);
  }
  #pragma unroll
  for (int i = 0; i < 2; i++)
    #pragma unroll
    for (int j = 0; j < 4; j++)
      #pragma unroll
      for (int r = 0; r < 4; r++) {
        int row = wm2 + i * 16 + quad * 4 + r;
        int col = j * 16 + lrow;
        ctxc[(size_t)(nl * 128 + row) * 768 + h * 64 + col] = f2b(o[i][j][r]);
      }
}

// ---------------- embedding + LN (wave per token) ----------------
__global__ __launch_bounds__(256) void embed_ln(
    const int* __restrict__ ids, const float* __restrict__ wemb,
    const float* __restrict__ pemb, const float* __restrict__ temb,
    const float* __restrict__ g, const float* __restrict__ b,
    float* __restrict__ xf, ushort* __restrict__ xb) {
  int tok = blockIdx.x * 4 + (threadIdx.x >> 6);
  int lane = threadIdx.x & 63;
  int t = tok & 127;
  int id = ids[tok];
  float v[12];
  float s = 0.f;
  #pragma unroll
  for (int k = 0; k < 12; k++) {
    int d = k * 64 + lane;
    v[k] = wemb[(size_t)id * 768 + d] + pemb[(size_t)(t + 2) * 768 + d] + temb[d];
    s += v[k];
  }
  #pragma unroll
  for (int o = 32; o; o >>= 1) s += __shfl_xor(s, o, 64);
  float mean = s * (1.f / 768.f);
  float vs = 0.f;
  #pragma unroll
  for (int k = 0; k < 12; k++) { float d = v[k] - mean; vs += d * d; }
  #pragma unroll
  for (int o = 32; o; o >>= 1) vs += __shfl_xor(vs, o, 64);
  float rstd = rsqrtf(vs * (1.f / 768.f) + 1e-5f);
  #pragma unroll
  for (int k = 0; k < 12; k++) {
    int d = k * 64 + lane;
    float ov = (v[k] - mean) * rstd * g[d] + b[d];
    xf[(size_t)tok * 768 + d] = ov;
    xb[(size_t)tok * 768 + d] = f2b(ov);
  }
}

// ---------------- in-place LN: x = LN(x) (wave per token) ----------------
__global__ __launch_bounds__(256) void ln_inplace(
    float* __restrict__ xf, const float* __restrict__ g, const float* __restrict__ b,
    ushort* __restrict__ xb) {
  int tok = blockIdx.x * 4 + (threadIdx.x >> 6);
  int lane = threadIdx.x & 63;
  float v[12];
  float s = 0.f;
  #pragma unroll
  for (int k = 0; k < 12; k++) { v[k] = xf[(size_t)tok * 768 + k * 64 + lane]; s += v[k]; }
  #pragma unroll
  for (int o = 32; o; o >>= 1) s += __shfl_xor(s, o, 64);
  float mean = s * (1.f / 768.f);
  float vs = 0.f;
  #pragma unroll
  for (int k = 0; k < 12; k++) { float d = v[k] - mean; vs += d * d; }
  #pragma unroll
  for (int o = 32; o; o >>= 1) vs += __shfl_xor(vs, o, 64);
  float rstd = rsqrtf(vs * (1.f / 768.f) + 1e-5f);
  #pragma unroll
  for (int k = 0; k < 12; k++) {
    int d = k * 64 + lane;
    float ov = (v[k] - mean) * rstd * g[d] + b[d];
    xf[(size_t)tok * 768 + d] = ov;
    xb[(size_t)tok * 768 + d] = f2b(ov);
  }
}

// ---------------- pooler gather ----------------
__global__ void gather_cls(const float* __restrict__ xf, ushort* __restrict__ out) {
  int n = blockIdx.x;
  for (int d = threadIdx.x; d < 768; d += 256)
    out[(size_t)n * 768 + d] = f2b(xf[(size_t)n * 128 * 768 + d]);
}

// ---------------- GAT pieces ----------------
__device__ __forceinline__ float blockSum256(float v) {
  __shared__ float sb[4];
  #pragma unroll
  for (int o = 32; o; o >>= 1) v += __shfl_xor(v, o, 64);
  int w = threadIdx.x >> 6;
  __syncthreads();
  if ((threadIdx.x & 63) == 0) sb[w] = v;
  __syncthreads();
  return sb[0] + sb[1] + sb[2] + sb[3];
}

__global__ __launch_bounds__(256) void gat_coeff(
    const float* __restrict__ h, const float* __restrict__ asrc,
    const float* __restrict__ adst, float* __restrict__ asr, float* __restrict__ ads,
    int ncols, int heads) {
  int n = blockIdx.x;
  int cc = ncols / heads;
  for (int hh = 0; hh < heads; hh++) {
    float vs = 0.f, vd = 0.f;
    if ((int)threadIdx.x < cc) {
      float hv = h[(size_t)n * ncols + hh * cc + threadIdx.x];
      vs = hv * asrc[hh * cc + threadIdx.x];
      vd = hv * adst[hh * cc + threadIdx.x];
    }
    float ss = blockSum256(vs);
    float sd = blockSum256(vd);
    if (threadIdx.x == 0) { asr[n * heads + hh] = ss; ads[n * heads + hh] = sd; }
  }
}

__global__ void gat_init(float* m, float* s, float* agg, int heads, int aggCols) {
  int n = blockIdx.x;
  if ((int)threadIdx.x < heads) {
    m[n * heads + threadIdx.x] = -1e30f;
    s[n * heads + threadIdx.x] = 0.f;
  }
  for (int c = threadIdx.x; c < aggCols; c += 256) agg[(size_t)n * aggCols + c] = 0.f;
}

__global__ void gat_edge_max(const int* __restrict__ ei, const float* __restrict__ asr,
                             const float* __restrict__ ads, float* __restrict__ m,
                             int heads, int E) {
  int e = blockIdx.x * 256 + threadIdx.x;
  if (e >= E + 512) return;
  int s, d;
  if (e < E) { s = ei[e]; d = ei[E + e]; } else { s = d = e - E; }
  for (int hh = 0; hh < heads; hh++) {
    float v = asr[s * heads + hh] + ads[d * heads + hh];
    v = v > 0.f ? v : 0.2f * v;
    atomicMaxFloat(&m[d * heads + hh], v);
  }
}

__global__ void gat_edge_agg(const int* __restrict__ ei, const float* __restrict__ asr,
                             const float* __restrict__ ads, const float* __restrict__ m,
                             const float* __restrict__ hfeat, float* __restrict__ sden,
                             float* __restrict__ agg, int heads, int cc, int E) {
  int e = blockIdx.x;
  int s, d;
  if (e < E) { s = ei[e]; d = ei[E + e]; } else { s = d = e - E; }
  int ncols = heads * cc;
  for (int hh = 0; hh < heads; hh++) {
    float v = asr[s * heads + hh] + ads[d * heads + hh];
    v = v > 0.f ? v : 0.2f * v;
    float p = expf(v - m[d * heads + hh]);
    if (threadIdx.x == 0) atomicAdd(&sden[d * heads + hh], p);
    int c = hh * cc + threadIdx.x;
    atomicAdd(&agg[(size_t)d * ncols + c], p * hfeat[(size_t)s * ncols + c]);
  }
}

__global__ void gat_finalize(const float* __restrict__ agg, const float* __restrict__ sden,
                             const float* __restrict__ bias, float* outF, ushort* outB,
                             float* outExtra, int heads, int cc, int doElu) {
  int n = blockIdx.x;
  int ncols = heads * cc;
  for (int c = threadIdx.x; c < ncols; c += blockDim.x) {
    int hh = c / cc;
    float v = agg[(size_t)n * ncols + c] / (sden[n * heads + hh] + 1e-16f) + bias[c];
    if (doElu) v = v > 0.f ? v : expm1f(v);
    if (outF) outF[(size_t)n * ncols + c] = v;
    outB[(size_t)n * ncols + c] = f2b(v);
    if (outExtra) outExtra[(size_t)n * ncols + c] = v;
  }
}

// ---------------- heads ----------------
__global__ __launch_bounds__(256) void feat_norm(const float* __restrict__ f,
                                                 float* __restrict__ out) {
  int n = blockIdx.x * 2 + (threadIdx.x >> 7);
  int lane = threadIdx.x & 127;
  int l64 = lane & 63;
  float x = f[n * 128 + lane];
  float v = x * x;
  __shared__ float sb[4];
  #pragma unroll
  for (int o = 32; o; o >>= 1) v += __shfl_xor(v, o, 64);
  int w = threadIdx.x >> 6;
  __syncthreads();
  if (l64 == 0) sb[w] = v;
  __syncthreads();
  float ss = sb[(threadIdx.x >> 7) * 2] + sb[(threadIdx.x >> 7) * 2 + 1];
  float sc = 1.f / fmaxf(sqrtf(ss), 1e-12f);
  out[n * 128 + lane] = x * sc;
}

__global__ void cls_head(const float* __restrict__ h2, const float* __restrict__ w,
                         const float* __restrict__ b, float* __restrict__ out) {
  int idx = blockIdx.x * 256 + threadIdx.x;
  if (idx >= 1024) return;
  int n = idx >> 1, c = idx & 1;
  float acc = b[c];
  for (int k = 0; k < 128; k++) acc += h2[n * 128 + k] * w[k * 2 + c];
  out[idx] = acc;
}

// ==================================================================================
extern "C" void kernel_launch(void* const* d_in, const int* in_sizes, int n_in,
                              void* d_out, int out_size, void* d_ws, size_t ws_size,
                              hipStream_t stream) {
  const int*   input_ids = (const int*)d_in[0];
  const int*   attn_mask = (const int*)d_in[1];
  const int*   edge_idx  = (const int*)d_in[2];
  const float* word_emb  = (const float*)d_in[3];
  const float* pos_emb   = (const float*)d_in[4];
  const float* type_emb  = (const float*)d_in[5];
  const float* ln_emb_s  = (const float*)d_in[6];
  const float* ln_emb_b  = (const float*)d_in[7];
  const float* Wqkv      = (const float*)d_in[8];
  const float* bqkv      = (const float*)d_in[9];
  const float* Wo        = (const float*)d_in[10];
  const float* bo        = (const float*)d_in[11];
  const float* ln1_s     = (const float*)d_in[12];
  const float* ln1_b     = (const float*)d_in[13];
  const float* Wff1      = (const float*)d_in[14];
  const float* bff1      = (const float*)d_in[15];
  const float* Wff2      = (const float*)d_in[16];
  const float* bff2      = (const float*)d_in[17];
  const float* ln2_s     = (const float*)d_in[18];
  const float* ln2_b     = (const float*)d_in[19];
  const float* pool_w    = (const float*)d_in[20];
  const float* pool_b    = (const float*)d_in[21];
  const float* gat1_w    = (const float*)d_in[22];
  const float* gat1_asrc = (const float*)d_in[23];
  const float* gat1_adst = (const float*)d_in[24];
  const float* gat1_b    = (const float*)d_in[25];
  const float* gat2_w    = (const float*)d_in[26];
  const float* gat2_asrc = (const float*)d_in[27];
  const float* gat2_adst = (const float*)d_in[28];
  const float* gat2_b    = (const float*)d_in[29];
  const float* proj_w1   = (const float*)d_in[30];
  const float* proj_b1   = (const float*)d_in[31];
  const float* proj_w2   = (const float*)d_in[32];
  const float* proj_b2   = (const float*)d_in[33];
  const float* cls_w     = (const float*)d_in[34];
  const float* cls_b     = (const float*)d_in[35];
  float* out = (float*)d_out;

  const int E = in_sizes[2] / 2;   // 32768
  const int ET = E + 512;
  const int M = 512 * 128;         // 65536 tokens
  const int CH = 16384;            // tokens per chunk (128 seqs)

  char* cur = (char*)d_ws;
  auto alloc = [&](size_t bytes) -> void* {
    void* p = (void*)cur;
    cur += (bytes + 255) & ~(size_t)255;
    return p;
  };

  // per-layer weight staging (reused each layer)
  ushort* WqkvT = (ushort*)alloc((size_t)2304 * 768 * 2);
  ushort* WoT   = (ushort*)alloc((size_t)768 * 768 * 2);
  ushort* Wff1T = (ushort*)alloc((size_t)3072 * 768 * 2);
  ushort* Wff2T = (ushort*)alloc((size_t)768 * 3072 * 2);
  // head weights
  ushort* PoolT = (ushort*)alloc((size_t)768 * 768 * 2);
  ushort* G1T   = (ushort*)alloc((size_t)1024 * 768 * 2);
  ushort* G2T   = (ushort*)alloc((size_t)128 * 1024 * 2);
  ushort* P1T   = (ushort*)alloc((size_t)128 * 128 * 2);
  ushort* P2T   = (ushort*)alloc((size_t)128 * 128 * 2);
  // activations
  float*  x_f32 = (float*)alloc((size_t)M * 768 * 4);    // 201.3 MB residual stream
  ushort* x_bf  = (ushort*)alloc((size_t)M * 768 * 2);   // 100.7 MB
  char*   arena = (char*)alloc((size_t)CH * 3072 * 2);   // 100.7 MB: qkvc+ctxc | ffc
  ushort* qkvc  = (ushort*)arena;                        // [CH,2304] = 75.5 MB
  ushort* ctxc  = (ushort*)(arena + (size_t)CH * 2304 * 2);  // [CH,768] = 25.2 MB
  ushort* ffc   = (ushort*)arena;                        // [CH,3072] = 100.7 MB
  // heads / GAT
  ushort* cls_bf   = (ushort*)alloc((size_t)512 * 768 * 2);
  ushort* htext_bf = (ushort*)alloc((size_t)512 * 768 * 2);
  float*  h1g      = (float*)alloc((size_t)512 * 1024 * 4);
  float*  asr1     = (float*)alloc(512 * 4 * 4);
  float*  ads1     = (float*)alloc(512 * 4 * 4);
  float*  m1       = (float*)alloc(512 * 4 * 4);
  float*  s1       = (float*)alloc(512 * 4 * 4);
  float*  agg1     = (float*)alloc((size_t)512 * 1024 * 4);
  ushort* h1_bf    = (ushort*)alloc((size_t)512 * 1024 * 2);
  float*  h2g      = (float*)alloc((size_t)512 * 128 * 4);
  float*  asr2     = (float*)alloc(512 * 4);
  float*  ads2     = (float*)alloc(512 * 4);
  float*  m2       = (float*)alloc(512 * 4);
  float*  s2       = (float*)alloc(512 * 4);
  float*  agg2     = (float*)alloc((size_t)512 * 128 * 4);
  float*  h2f      = (float*)alloc((size_t)512 * 128 * 4);
  ushort* h2_bf    = (ushort*)alloc((size_t)512 * 128 * 2);
  ushort* p1_bf    = (ushort*)alloc((size_t)512 * 128 * 2);
  float*  featpre  = (float*)alloc((size_t)512 * 128 * 4);

  auto T = [&](const float* in, ushort* o, int K, int N) {
    transpose_to_bf16<<<dim3(K / 32, N / 32), dim3(32, 8), 0, stream>>>(in, o, K, N);
  };

  // head weights once
  T(pool_w, PoolT, 768, 768);
  T(gat1_w, G1T, 768, 1024);
  T(gat2_w, G2T, 1024, 128);
  T(proj_w1, P1T, 128, 128);
  T(proj_w2, P2T, 128, 128);

  embed_ln<<<M / 4, 256, 0, stream>>>(input_ids, word_emb, pos_emb, type_emb,
                                      ln_emb_s, ln_emb_b, x_f32, x_bf);

  for (int i = 0; i < 12; i++) {
    T(Wqkv + (size_t)i * 768 * 2304, WqkvT, 768, 2304);
    T(Wo   + (size_t)i * 768 * 768,  WoT,   768, 768);
    T(Wff1 + (size_t)i * 768 * 3072, Wff1T, 768, 3072);
    T(Wff2 + (size_t)i * 3072 * 768, Wff2T, 3072, 768);

    // attention (chunked over 4 groups of 128 sequences)
    for (int c = 0; c < 4; c++) {
      size_t off = (size_t)c * CH;
      gemm_bt<<<dim3(CH / 128, 18), 256, 0, stream>>>(
          x_bf + off * 768, WqkvT, bqkv + (size_t)i * 2304,
          nullptr, qkvc, CH, 2304, 768, 768, 768, 0, 0);
      fused_attn<<<1536, 256, 0, stream>>>(qkvc, attn_mask, ctxc, c * 128);
      gemm_bt<<<dim3(CH / 128, 6), 256, 0, stream>>>(
          ctxc, WoT, bo + (size_t)i * 768,
          x_f32 + off * 768, nullptr, CH, 768, 768, 768, 768, 0, 1);
    }
    ln_inplace<<<M / 4, 256, 0, stream>>>(x_f32, ln1_s + (size_t)i * 768,
                                          ln1_b + (size_t)i * 768, x_bf);
    // FFN (chunked)
    for (int c = 0; c < 4; c++) {
      size_t off = (size_t)c * CH;
      gemm_bt<<<dim3(CH / 128, 24), 256, 0, stream>>>(
          x_bf + off * 768, Wff1T, bff1 + (size_t)i * 3072,
          nullptr, ffc, CH, 3072, 768, 768, 768, 1, 0);
      gemm_bt<<<dim3(CH / 128, 6), 256, 0, stream>>>(
          ffc, Wff2T, bff2 + (size_t)i * 768,
          x_f32 + off * 768, nullptr, CH, 768, 3072, 3072, 3072, 0, 1);
    }
    ln_inplace<<<M / 4, 256, 0, stream>>>(x_f32, ln2_s + (size_t)i * 768,
                                          ln2_b + (size_t)i * 768, x_bf);
  }

  gather_cls<<<512, 256, 0, stream>>>(x_f32, cls_bf);
  gemm_bt<<<dim3(4, 6), 256, 0, stream>>>(cls_bf, PoolT, pool_b, nullptr, htext_bf,
                                          512, 768, 768, 768, 768, 2, 0);
  gemm_bt<<<dim3(4, 8), 256, 0, stream>>>(htext_bf, G1T, nullptr, h1g, nullptr,
                                          512, 1024, 768, 768, 768, 0, 0);
  gat_coeff<<<512, 256, 0, stream>>>(h1g, gat1_asrc, gat1_adst, asr1, ads1, 1024, 4);
  gat_init<<<512, 256, 0, stream>>>(m1, s1, agg1, 4, 1024);
  gat_edge_max<<<(ET + 255) / 256, 256, 0, stream>>>(edge_idx, asr1, ads1, m1, 4, E);
  gat_edge_agg<<<ET, 256, 0, stream>>>(edge_idx, asr1, ads1, m1, h1g, s1, agg1, 4, 256, E);
  gat_finalize<<<512, 256, 0, stream>>>(agg1, s1, gat1_b, nullptr, h1_bf, nullptr, 4, 256, 1);

  gemm_bt<<<dim3(4, 1), 256, 0, stream>>>(h1_bf, G2T, nullptr, h2g, nullptr,
                                          512, 128, 1024, 1024, 1024, 0, 0);
  gat_coeff<<<512, 256, 0, stream>>>(h2g, gat2_asrc, gat2_adst, asr2, ads2, 128, 1);
  gat_init<<<512, 256, 0, stream>>>(m2, s2, agg2, 1, 128);
  gat_edge_max<<<(ET + 255) / 256, 256, 0, stream>>>(edge_idx, asr2, ads2, m2, 1, E);
  gat_edge_agg<<<ET, 128, 0, stream>>>(edge_idx, asr2, ads2, m2, h2g, s2, agg2, 1, 128, E);
  gat_finalize<<<512, 256, 0, stream>>>(agg2, s2, gat2_b, h2f, h2_bf, out + 66560, 1, 128, 0);

  gemm_bt<<<dim3(4, 1), 256, 0, stream>>>(h2_bf, P1T, proj_b1, nullptr, p1_bf,
                                          512, 128, 128, 128, 128, 3, 0);
  gemm_bt<<<dim3(4, 1), 256, 0, stream>>>(p1_bf, P2T, proj_b2, featpre, nullptr,
                                          512, 128, 128, 128, 128, 0, 0);
  feat_norm<<<256, 256, 0, stream>>>(featpre, out + 1024);
  cls_head<<<4, 256, 0, stream>>>(h2f, cls_w, cls_b, out);
}